// Round 16
// baseline (684.518 us; speedup 1.0000x reference)
//
#include <hip/hip_runtime.h>
#include <hip/hip_bf16.h>
#include <stdint.h>

typedef __attribute__((ext_vector_type(8))) short short8;
typedef __attribute__((ext_vector_type(4))) float f32x4;
typedef __attribute__((ext_vector_type(4))) float float4v;
typedef __attribute__((ext_vector_type(4))) int int4v;

#define MDIM 8192
#define NDIM 11008
#define KDIM 4096
#define BKI  64                /* i8 K-tile */
#define NTI  (KDIM / BKI)      /* 64 K-tiles */
#define NBMI (MDIM / 128)      /* 64 */
#define NBN64 (NDIM / 64)      /* 172 */
#define NXB  (MDIM / 16)       /* 512 x row-blocks */

// ws layout (bytes)
#define AQ_OFF  0ull                                  /* A fragment-linear, 32 MB */
#define WQ_OFF  ((size_t)MDIM * KDIM)                 /* 33554432 */
#define SXT_OFF (WQ_OFF + (size_t)NDIM * KDIM)        /* + 45088768 */
#define SWT_OFF (SXT_OFF + 16ull * MDIM * 4)          /* + 524288 */
#define WS_NEED (SWT_OFF + 16ull * NDIM * 4)          /* ~79.9 MB */

static __device__ __forceinline__ unsigned short f2bf(float f) {
  union { float f; unsigned int u; } v;
  v.f = f;
  unsigned int r = v.u + 0x7FFFu + ((v.u >> 16) & 1u);
  return (unsigned short)(r >> 16);
}

#define GLDS16(g, l) __builtin_amdgcn_global_load_lds(                         \
    (const __attribute__((address_space(1))) void*)(g),                        \
    (__attribute__((address_space(3))) void*)(l), 16, 0, 0)

// ---------------- pass 1 (fused) — r15-verified ------------------------------
// blocks [0, NXB): 16 x-rows -> int8, FRAGMENT-LINEAR:
//   aqf[((r16*NTI + kt)<<10) + l*16] = x_q[r16*16 + (l&15)][kt*64+(l>>4)*16 ..]
// blocks [NXB, NXB+NDIM): w row -> row-major int8 pack + swT.
__global__ __launch_bounds__(256) void prep_all(
    const float* __restrict__ x, char* __restrict__ aqf, float* __restrict__ sxT,
    const int* __restrict__ qw, const float* __restrict__ scale,
    char* __restrict__ wq, float* __restrict__ swT) {
  const int t = threadIdx.x;
  if (blockIdx.x < NXB) {
    __shared__ char sq[16 * 272];
    const int r16 = blockIdx.x;
    const int row = t >> 4;
    const int seg = t & 15;
    for (int j = 0; j < 16; ++j) {
      const float* p = x + ((size_t)(r16 * 16 + row)) * KDIM + j * 256 + seg * 16;
      float4v v[4];
#pragma unroll
      for (int c = 0; c < 4; ++c) v[c] = *(const float4v*)(p + c * 4);
      float amax = 0.f;
#pragma unroll
      for (int c = 0; c < 4; ++c)
#pragma unroll
        for (int e = 0; e < 4; ++e) amax = fmaxf(amax, fabsf(v[c][e]));
#pragma unroll
      for (int d = 1; d < 16; d <<= 1) amax = fmaxf(amax, __shfl_xor(amax, d));
      amax = fmaxf(amax, 1e-20f);
      if (seg == 0)
        sxT[(size_t)j * MDIM + r16 * 16 + row] = amax * (1.0f / 127.0f);
      const float inv = 127.0f / amax;
      int4v o;
#pragma unroll
      for (int c = 0; c < 4; ++c) {
        unsigned int r = 0;
#pragma unroll
        for (int e = 0; e < 4; ++e) {
          int q = __float2int_rn(v[c][e] * inv);
          r |= ((unsigned int)(q & 255)) << (8 * e);
        }
        o[c] = (int)r;
      }
      *(int4v*)(sq + row * 272 + seg * 16) = o;
      __syncthreads();
      {
        const int ktl = t >> 6;
        const int l = t & 63;
        int4v vv = *(const int4v*)(sq + (l & 15) * 272 + ktl * 64 + (l >> 4) * 16);
        *(int4v*)(aqf + (((size_t)r16 * NTI + j * 4 + ktl) << 10) + l * 16) = vv;
      }
      __syncthreads();
    }
  } else {
    const int row = blockIdx.x - NXB;
    const int* p = qw + (size_t)row * KDIM + t * 16;
    int4v v[4];
#pragma unroll
    for (int c = 0; c < 4; ++c) v[c] = *(const int4v*)(p + c * 4);
    int4v o;
#pragma unroll
    for (int c = 0; c < 4; ++c) {
      unsigned int r = 0;
#pragma unroll
      for (int e = 0; e < 4; ++e) r |= ((unsigned int)(v[c][e] & 255)) << (8 * e);
      o[c] = (int)r;
    }
    *(int4v*)(wq + (size_t)row * KDIM + t * 16) = o;
    if ((t & 15) == 0)
      swT[(size_t)(t >> 4) * NDIM + row] = 1.0f / scale[(size_t)row * 16 + (t >> 4)];
  }
}

// ---------------- pass 2: 128x64 i8 GEMM, 3 blocks/CU ------------------------
// Wave tile 64x32 (acc halved -> ~140 regs -> 3 waves/SIMD). A fragment-linear
// direct-to-register (r15); B via r9 LDS path, 4 strips of 16 cols, 1 GLDS per
// wave per tile. 28KB LDS. FIFO-exact: per tile issue [A(t+1)x4, B(t+3)x1];
// steady vmcnt(6) drains {B(t+1), A(t)x4}; tail 6->5->4->0.
__global__ __launch_bounds__(256, 3) void gemm_i8(
    const char* __restrict__ aqf, const char* __restrict__ wq,
    const float* __restrict__ sxT, const float* __restrict__ swT,
    const float* __restrict__ bias, float* __restrict__ out)
{
  __shared__ unsigned char lds[28672];
  unsigned char* ldsB = lds;              // [4][4096]: 4 strips x 16 rows x 64B
  float* sxl = (float*)(lds + 16384);     // [16][128] row scales (8KB)
  float* swl = (float*)(lds + 24576);     // [16][64]  col inv-scales (4KB)

  const int t = threadIdx.x;
  const int lane = t & 63;
  const int w = t >> 6;        // wave 0..3
  const int wr = w >> 1;       // 0..1  (A 64-row half)
  const int wc = w & 1;        // 0..1  (B 32-col half)
  const int lh = lane >> 4;    // 0..3
  const int l15 = lane & 15;

  // XCD-bijective swizzle: 11008 = 8 * 1376
  const int bid = blockIdx.x;
  const int swz = (bid & 7) * (NBMI * NBN64 / 8) + (bid >> 3);
  const int bm = swz / NBN64;
  const int bn = swz % NBN64;

  // B staging (r9): lane-adjacent source, XOR granule; one 16-col strip/wave
  const int srow16 = lane >> 2;
  const int q = (lane & 3) ^ (srow16 & 3) ^ ((srow16 >> 2) & 3);
  const size_t srcOff = (size_t)srow16 * KDIM + q * 16;
  const char* bS = wq + ((size_t)(bn * 64 + w * 16)) * KDIM + srcOff;
  const int f15 = (l15 & 3) ^ (l15 >> 2);

  // A fragment-linear base: wave's 4 row-blocks start at bm*8 + wr*4
  const char* aF = aqf + (((size_t)(bm * 8 + wr * 4) * NTI) << 10) + lane * 16;

  // bias: load early and pin
  float bias_v[2];
#pragma unroll
  for (int n = 0; n < 2; ++n) {
    bias_v[n] = bias[bn * 64 + wc * 32 + n * 16 + l15];
    asm volatile("" :: "v"(bias_v[n]));
  }

  // stage scale tables into LDS
  {
    const int tg = t >> 4;                 // 0..15
    const int tc = (t & 15) * 8;
    float4v a0 = *(const float4v*)(sxT + (size_t)tg * MDIM + bm * 128 + tc);
    float4v a1 = *(const float4v*)(sxT + (size_t)tg * MDIM + bm * 128 + tc + 4);
    *(float4v*)(sxl + tg * 128 + tc)     = a0;
    *(float4v*)(sxl + tg * 128 + tc + 4) = a1;
    const int tc2 = (t & 15) * 4;          // 64 cols
    float4v b0 = *(const float4v*)(swT + (size_t)tg * NDIM + bn * 64 + tc2);
    *(float4v*)(swl + tg * 64 + tc2) = b0;
  }
  __syncthreads();   // publishes tables; drains vmcnt to 0

  f32x4 accf[4][2];
  int4v acci[4][2];
#pragma unroll
  for (int m = 0; m < 4; ++m)
#pragma unroll
    for (int n = 0; n < 2; ++n) {
      accf[m][n] = (f32x4){0.f, 0.f, 0.f, 0.f};
      acci[m][n] = (int4v){0, 0, 0, 0};
    }

#define ALOAD(ABUF, kt) {                                                      \
  _Pragma("unroll")                                                            \
  for (int m = 0; m < 4; ++m)                                                  \
    ABUF[m] = *(const int4v*)(aF + (((size_t)m * NTI + (kt)) << 10)); }

#define STAGE_B(buf, kt)                                                       \
  GLDS16(bS + (kt) * BKI, ldsB + (buf) * 4096 + w * 1024);

#define RD_B(buf, n) (*(const int4v*)(ldsB + (buf) * 4096 +                    \
                      (wc * 2 + (n)) * 1024 + l15 * 64 + ((lh ^ f15) << 4)))

#define VMW(N) asm volatile("s_waitcnt vmcnt(" N ")" ::: "memory");

// tile t (bbuf = t&3): issue A(t+1)->ANXT, B-stage(t+3); ds_read B(t);
// counted wait; 8 MFMA on ACUR; optional fixup; barrier.
#define TILE(bbuf, kt, ACUR, ANXT, DOLOADA, DOSTAGEB, WAITN, DOFIX, DOBAR) {   \
  if (DOLOADA) ALOAD(ANXT, (kt) + 1);                                          \
  __builtin_amdgcn_sched_barrier(0);                                           \
  if (DOSTAGEB) STAGE_B(((bbuf) + 3) & 3, (kt) + 3);                           \
  __builtin_amdgcn_sched_barrier(0);                                           \
  int4v b[2];                                                                  \
  b[0] = RD_B(bbuf, 0);                                                        \
  b[1] = RD_B(bbuf, 1);                                                        \
  float4v sxv[4]; float swv[2];                                                \
  if (DOFIX) {                                                                 \
    const int g = (kt) >> 2;                                                   \
    _Pragma("unroll")                                                          \
    for (int m = 0; m < 4; ++m)                                                \
      sxv[m] = *(const float4v*)(sxl + g * 128 + wr * 64 + m * 16 + lh * 4);   \
    _Pragma("unroll")                                                          \
    for (int n = 0; n < 2; ++n)                                                \
      swv[n] = swl[g * 64 + wc * 32 + n * 16 + l15];                           \
  }                                                                            \
  VMW(WAITN)                                                                   \
  __builtin_amdgcn_sched_barrier(0);                                           \
  __builtin_amdgcn_s_setprio(1);                                               \
  _Pragma("unroll")                                                            \
  for (int m = 0; m < 4; ++m)                                                  \
    _Pragma("unroll")                                                          \
    for (int n = 0; n < 2; ++n)                                                \
      acci[m][n] = __builtin_amdgcn_mfma_i32_16x16x64_i8(ACUR[m], b[n],        \
                                                         acci[m][n], 0, 0, 0); \
  __builtin_amdgcn_s_setprio(0);                                               \
  if (DOFIX) {                                                                 \
    _Pragma("unroll")                                                          \
    for (int m = 0; m < 4; ++m)                                                \
      _Pragma("unroll")                                                        \
      for (int n = 0; n < 2; ++n) {                                            \
        _Pragma("unroll")                                                      \
        for (int j = 0; j < 4; ++j)                                            \
          accf[m][n][j] += (float)acci[m][n][j] * (sxv[m][j] * swv[n]);        \
        acci[m][n] = (int4v){0, 0, 0, 0};                                      \
      }                                                                        \
  }                                                                            \
  if (DOBAR) __builtin_amdgcn_s_barrier(); }

  int4v A0f[4], A1f[4];

  // prologue: B0, B1, A0(x4), B2 = 7 in queue; drain B0 -> vmcnt(6); publish
  STAGE_B(0, 0);
  STAGE_B(1, 1);
  __builtin_amdgcn_sched_barrier(0);
  ALOAD(A0f, 0);
  __builtin_amdgcn_sched_barrier(0);
  STAGE_B(2, 2);
  __builtin_amdgcn_sched_barrier(0);
  VMW("6")
  __builtin_amdgcn_s_barrier();

  // steady: entering t: [B(t+1), A(t)x4, B(t+2)] = 6; +5 issued; vmcnt(6)
  // drains exactly {B(t+1), A(t)x4}.
  for (int kt = 0; kt < NTI - 4; kt += 4) {
    TILE(0, kt,     A0f, A1f, 1, 1, "6", 0, 1)
    TILE(1, kt + 1, A1f, A0f, 1, 1, "6", 0, 1)
    TILE(2, kt + 2, A0f, A1f, 1, 1, "6", 0, 1)
    TILE(3, kt + 3, A1f, A0f, 1, 1, "6", 1, 1)
  }
  // tail: t60 steady (stages B63); t61 A-only -> vmcnt(5); t62 -> vmcnt(4);
  // t63 drain-all.
  TILE(0, NTI - 4, A0f, A1f, 1, 1, "6", 0, 1)
  TILE(1, NTI - 3, A1f, A0f, 1, 0, "5", 0, 1)
  TILE(2, NTI - 2, A0f, A1f, 1, 0, "4", 0, 1)
  TILE(3, NTI - 1, A1f, A0f, 0, 0, "0", 1, 0)

  // epilogue: bias + fp32 store (C/D map: col=lane&15, row=(lane>>4)*4+j)
#pragma unroll
  for (int m = 0; m < 4; ++m) {
    const int row0 = bm * 128 + wr * 64 + m * 16 + lh * 4;
#pragma unroll
    for (int n = 0; n < 2; ++n) {
      const int col = bn * 64 + wc * 32 + n * 16 + l15;
      const float bv_ = bias_v[n];
#pragma unroll
      for (int j = 0; j < 4; ++j)
        out[(size_t)(row0 + j) * NDIM + col] = accf[m][n][j] + bv_;
    }
  }
#undef TILE
#undef VMW
#undef RD_B
#undef STAGE_B
#undef ALOAD
}

// ---------------- fallback: fused single-pass (round-1 kernel) ----------------
__global__ __launch_bounds__(256, 2) void clinear_fused(
    const float* __restrict__ x,
    const int* __restrict__ qw,
    const float* __restrict__ scale,
    const float* __restrict__ bias,
    float* __restrict__ out)
{
  __shared__ unsigned char ldsA[128 * 64 * 2];
  __shared__ unsigned char ldsB[128 * 64 * 2];

  const int t = threadIdx.x;
  const int lane = t & 63;
  const int wave = t >> 6;
  const int wr = wave >> 1;
  const int wc = wave & 1;

  const int NBN = NDIM / 128;
  const int bid = blockIdx.x;
  const int cpx = ((MDIM / 128) * NBN) >> 3;
  const int swz = (bid & 7) * cpx + (bid >> 3);
  const int bm = swz / NBN;
  const int bn = swz % NBN;

  const int srow = t >> 1;
  const int shalf = t & 1;
  const float* aptr = x  + (size_t)(bm * 128 + srow) * KDIM + shalf * 32;
  const int*   bptr = qw + (size_t)(bn * 128 + srow) * KDIM + shalf * 32;
  const float* sptr = scale + (size_t)(bn * 128 + srow) * (KDIM / 256);
  const int arx = srow & 7;

  f32x4 acc[4][4];
#pragma unroll
  for (int i = 0; i < 4; ++i)
#pragma unroll
    for (int j = 0; j < 4; ++j)
      acc[i][j] = (f32x4){0.f, 0.f, 0.f, 0.f};

  float bias_v[4];
#pragma unroll
  for (int n = 0; n < 4; ++n)
    bias_v[n] = bias[bn * 128 + wc * 64 + n * 16 + (lane & 15)];

  for (int kt = 0; kt < KDIM / 64; ++kt) {
    const int k0 = kt * 64;
    float4v av[8];
    int4v   bv[8];
#pragma unroll
    for (int j = 0; j < 8; ++j) av[j] = *(const float4v*)(aptr + k0 + 4 * j);
#pragma unroll
    for (int j = 0; j < 8; ++j) bv[j] = *(const int4v*)(bptr + k0 + 4 * j);
    const float inv = 1.0f / sptr[k0 >> 8];

    __syncthreads();
#pragma unroll
    for (int c = 0; c < 4; ++c) {
      short8 pa, pb;
#pragma unroll
      for (int e = 0; e < 8; ++e) {
        const int v = c * 8 + e;
        pa[e] = (short)f2bf(av[v >> 2][v & 3]);
        pb[e] = (short)f2bf((float)bv[v >> 2][v & 3] * inv);
      }
      const int cc = shalf * 4 + c;
      *(short8*)(ldsA + srow * 128 + ((cc ^ arx) << 4)) = pa;
      *(short8*)(ldsB + srow * 128 + ((cc ^ arx) << 4)) = pb;
    }
    __syncthreads();

    short8 af[4][2], bfr[4][2];
#pragma unroll
    for (int m = 0; m < 4; ++m) {
      const int r = wr * 64 + m * 16 + (lane & 15);
      const int rx = r & 7;
#pragma unroll
      for (int ks = 0; ks < 2; ++ks) {
        const int ch = ks * 4 + (lane >> 4);
        af[m][ks] = *(const short8*)(ldsA + r * 128 + ((ch ^ rx) << 4));
      }
    }
#pragma unroll
    for (int n = 0; n < 4; ++n) {
      const int r = wc * 64 + n * 16 + (lane & 15);
      const int rx = r & 7;
#pragma unroll
      for (int ks = 0; ks < 2; ++ks) {
        const int ch = ks * 4 + (lane >> 4);
        bfr[n][ks] = *(const short8*)(ldsB + r * 128 + ((ch ^ rx) << 4));
      }
    }
#pragma unroll
    for (int ks = 0; ks < 2; ++ks)
#pragma unroll
      for (int m = 0; m < 4; ++m)
#pragma unroll
        for (int n = 0; n < 4; ++n)
          acc[m][n] = __builtin_amdgcn_mfma_f32_16x16x32_bf16(
              af[m][ks], bfr[n][ks], acc[m][n], 0, 0, 0);
  }

#pragma unroll
  for (int m = 0; m < 4; ++m) {
    const int row0 = bm * 128 + wr * 64 + m * 16 + (lane >> 4) * 4;
#pragma unroll
    for (int n = 0; n < 4; ++n) {
      const int col = bn * 128 + wc * 64 + n * 16 + (lane & 15);
      const float bv_ = bias_v[n];
#pragma unroll
      for (int j = 0; j < 4; ++j)
        out[(size_t)(row0 + j) * NDIM + col] = acc[m][n][j] + bv_;
    }
  }
}

extern "C" void kernel_launch(void* const* d_in, const int* in_sizes, int n_in,
                              void* d_out, int out_size, void* d_ws, size_t ws_size,
                              hipStream_t stream) {
  const float* x     = (const float*)d_in[0];
  const int*   qw    = (const int*)d_in[1];
  const float* scale = (const float*)d_in[2];
  const float* bias  = (const float*)d_in[3];
  float* out = (float*)d_out;

  if (ws_size >= WS_NEED) {
    char*  aqf = (char*)d_ws + AQ_OFF;
    char*  wqb = (char*)d_ws + WQ_OFF;
    float* sxT = (float*)((char*)d_ws + SXT_OFF);
    float* swT = (float*)((char*)d_ws + SWT_OFF);
    hipLaunchKernelGGL(prep_all, dim3(NXB + NDIM), dim3(256), 0, stream,
                       x, aqf, sxT, qw, scale, wqb, swT);
    hipLaunchKernelGGL(gemm_i8, dim3(NBMI * NBN64), dim3(256), 0, stream,
                       aqf, wqb, sxT, swT, bias, out);
  } else {
    hipLaunchKernelGGL(clinear_fused, dim3((MDIM / 128) * (NDIM / 128)), dim3(256),
                       0, stream, x, qw, scale, bias, out);
  }
}

// Round 17
// 622.809 us; speedup vs baseline: 1.0991x; 1.0991x over previous
//
#include <hip/hip_runtime.h>
#include <hip/hip_bf16.h>
#include <stdint.h>

typedef __attribute__((ext_vector_type(8))) short short8;
typedef __attribute__((ext_vector_type(4))) float f32x4;
typedef __attribute__((ext_vector_type(4))) float float4v;
typedef __attribute__((ext_vector_type(4))) int int4v;

#define MDIM 8192
#define NDIM 11008
#define KDIM 4096
#define BKI  64                /* i8 K-tile */
#define NTI  (KDIM / BKI)      /* 64 K-tiles */
#define NBMI (MDIM / 128)      /* 64 */
#define NBNI (NDIM / 128)      /* 86 */
#define NXB  (MDIM / 16)       /* 512 x row-blocks */

// ws layout (bytes)
#define AQ_OFF  0ull                                  /* A fragment-linear, 32 MB */
#define WQ_OFF  ((size_t)MDIM * KDIM)                 /* 33554432 */
#define SXT_OFF (WQ_OFF + (size_t)NDIM * KDIM)        /* + 45088768 */
#define SWT_OFF (SXT_OFF + 16ull * MDIM * 4)          /* + 524288 */
#define WS_NEED (SWT_OFF + 16ull * NDIM * 4)          /* ~79.9 MB */

static __device__ __forceinline__ unsigned short f2bf(float f) {
  union { float f; unsigned int u; } v;
  v.f = f;
  unsigned int r = v.u + 0x7FFFu + ((v.u >> 16) & 1u);
  return (unsigned short)(r >> 16);
}

#define GLDS16(g, l) __builtin_amdgcn_global_load_lds(                         \
    (const __attribute__((address_space(1))) void*)(g),                        \
    (__attribute__((address_space(3))) void*)(l), 16, 0, 0)

// ---------------- pass 1 (fused) — r15-verified ------------------------------
__global__ __launch_bounds__(256) void prep_all(
    const float* __restrict__ x, char* __restrict__ aqf, float* __restrict__ sxT,
    const int* __restrict__ qw, const float* __restrict__ scale,
    char* __restrict__ wq, float* __restrict__ swT) {
  const int t = threadIdx.x;
  if (blockIdx.x < NXB) {
    __shared__ char sq[16 * 272];
    const int r16 = blockIdx.x;
    const int row = t >> 4;
    const int seg = t & 15;
    for (int j = 0; j < 16; ++j) {
      const float* p = x + ((size_t)(r16 * 16 + row)) * KDIM + j * 256 + seg * 16;
      float4v v[4];
#pragma unroll
      for (int c = 0; c < 4; ++c) v[c] = *(const float4v*)(p + c * 4);
      float amax = 0.f;
#pragma unroll
      for (int c = 0; c < 4; ++c)
#pragma unroll
        for (int e = 0; e < 4; ++e) amax = fmaxf(amax, fabsf(v[c][e]));
#pragma unroll
      for (int d = 1; d < 16; d <<= 1) amax = fmaxf(amax, __shfl_xor(amax, d));
      amax = fmaxf(amax, 1e-20f);
      if (seg == 0)
        sxT[(size_t)j * MDIM + r16 * 16 + row] = amax * (1.0f / 127.0f);
      const float inv = 127.0f / amax;
      int4v o;
#pragma unroll
      for (int c = 0; c < 4; ++c) {
        unsigned int r = 0;
#pragma unroll
        for (int e = 0; e < 4; ++e) {
          int q = __float2int_rn(v[c][e] * inv);
          r |= ((unsigned int)(q & 255)) << (8 * e);
        }
        o[c] = (int)r;
      }
      *(int4v*)(sq + row * 272 + seg * 16) = o;
      __syncthreads();
      {
        const int ktl = t >> 6;
        const int l = t & 63;
        int4v vv = *(const int4v*)(sq + (l & 15) * 272 + ktl * 64 + (l >> 4) * 16);
        *(int4v*)(aqf + (((size_t)r16 * NTI + j * 4 + ktl) << 10) + l * 16) = vv;
      }
      __syncthreads();
    }
  } else {
    const int row = blockIdx.x - NXB;
    const int* p = qw + (size_t)row * KDIM + t * 16;
    int4v v[4];
#pragma unroll
    for (int c = 0; c < 4; ++c) v[c] = *(const int4v*)(p + c * 4);
    int4v o;
#pragma unroll
    for (int c = 0; c < 4; ++c) {
      unsigned int r = 0;
#pragma unroll
      for (int e = 0; e < 4; ++e) r |= ((unsigned int)(v[c][e] & 255)) << (8 * e);
      o[c] = (int)r;
    }
    *(int4v*)(wq + (size_t)row * KDIM + t * 16) = o;
    if ((t & 15) == 0)
      swT[(size_t)(t >> 4) * NDIM + row] = 1.0f / scale[(size_t)row * 16 + (t >> 4)];
  }
}

// ---------------- pass 2: 128x128 i8 GEMM, super-tile schedule ---------------
// r15's exact data paths (A fragment-linear direct-to-reg; B via r9 LDS path,
// 4-deep), but sync amortized 2x: ONE vmcnt(0)+barrier per 2 K-tiles.
// Super S covers (kt, kt+1): reads B bufs {kt,kt+1}&3 (published by previous
// barrier), stages B(kt+2),B(kt+3) into the disjoint other two bufs, loads
// A(kt+2),A(kt+3) to regs; 32 MFMA; end-of-S drain budget = full super
// (>=1300 cyc > ~900 HBM latency).
__global__ __launch_bounds__(256, 2) void gemm_i8(
    const char* __restrict__ aqf, const char* __restrict__ wq,
    const float* __restrict__ sxT, const float* __restrict__ swT,
    const float* __restrict__ bias, float* __restrict__ out)
{
  __shared__ unsigned char lds[49152];
  unsigned char* ldsB = lds;              // [4][8192]: 8 strips x 16 rows x 64B
  float* sxl = (float*)(lds + 32768);     // [16][128] row scales
  float* swl = (float*)(lds + 40960);     // [16][128] col inv-scales

  const int t = threadIdx.x;
  const int lane = t & 63;
  const int w = t >> 6;        // wave 0..3
  const int wr = w >> 1;       // 0..1  (A 64-row half)
  const int wc = w & 1;        // 0..1  (B 64-col half)
  const int lh = lane >> 4;    // 0..3
  const int l15 = lane & 15;

  // XCD-bijective swizzle: 5504 = 8 * 688
  const int bid = blockIdx.x;
  const int swz = (bid & 7) * (NBMI * NBNI / 8) + (bid >> 3);
  const int bm = swz / NBNI;
  const int bn = swz % NBNI;

  // B staging (r9): lane-adjacent source, XOR granule
  const int srow16 = lane >> 2;
  const int q = (lane & 3) ^ (srow16 & 3) ^ ((srow16 >> 2) & 3);
  const size_t srcOff = (size_t)srow16 * KDIM + q * 16;
  const char* bS = wq + ((size_t)(bn * 128 + w * 32)) * KDIM + srcOff;
  const int f15 = (l15 & 3) ^ (l15 >> 2);

  // A fragment-linear base: wave's 4 row-blocks start at bm*8 + wr*4
  const char* aF = aqf + (((size_t)(bm * 8 + wr * 4) * NTI) << 10) + lane * 16;

  // bias: load early and pin
  float bias_v[4];
#pragma unroll
  for (int n = 0; n < 4; ++n) {
    bias_v[n] = bias[bn * 128 + wc * 64 + n * 16 + l15];
    asm volatile("" :: "v"(bias_v[n]));
  }

  // stage scale tables into LDS
  {
    const int tg = t >> 4;
    const int tc = (t & 15) * 8;
    float4v a0 = *(const float4v*)(sxT + (size_t)tg * MDIM + bm * 128 + tc);
    float4v a1 = *(const float4v*)(sxT + (size_t)tg * MDIM + bm * 128 + tc + 4);
    float4v b0 = *(const float4v*)(swT + (size_t)tg * NDIM + bn * 128 + tc);
    float4v b1 = *(const float4v*)(swT + (size_t)tg * NDIM + bn * 128 + tc + 4);
    *(float4v*)(sxl + tg * 128 + tc)     = a0;
    *(float4v*)(sxl + tg * 128 + tc + 4) = a1;
    *(float4v*)(swl + tg * 128 + tc)     = b0;
    *(float4v*)(swl + tg * 128 + tc + 4) = b1;
  }
  __syncthreads();   // publishes tables; drains vmcnt to 0

  f32x4 accf[4][4];
  int4v acci[4][4];
#pragma unroll
  for (int m = 0; m < 4; ++m)
#pragma unroll
    for (int n = 0; n < 4; ++n) {
      accf[m][n] = (f32x4){0.f, 0.f, 0.f, 0.f};
      acci[m][n] = (int4v){0, 0, 0, 0};
    }

#define ALOAD(ABUF, kt) {                                                      \
  _Pragma("unroll")                                                            \
  for (int m = 0; m < 4; ++m)                                                  \
    ABUF[m] = *(const int4v*)(aF + (((size_t)m * NTI + (kt)) << 10)); }

#define STAGE_B(buf, kt) {                                                     \
  GLDS16(bS + (kt) * BKI,             ldsB + (buf) * 8192 + w * 2048);         \
  GLDS16(bS + 16 * KDIM + (kt) * BKI, ldsB + (buf) * 8192 + w * 2048 + 1024); }

#define RD_B(buf, n) (*(const int4v*)(ldsB + (buf) * 8192 + wc * 4096 +        \
                      (n) * 1024 + l15 * 64 + ((lh ^ f15) << 4)))

#define VMW(N) asm volatile("s_waitcnt vmcnt(" N ")" ::: "memory");

#define MFMA16(AC, BARR) {                                                     \
  _Pragma("unroll")                                                            \
  for (int m = 0; m < 4; ++m)                                                  \
    _Pragma("unroll")                                                          \
    for (int n = 0; n < 4; ++n)                                                \
      acci[m][n] = __builtin_amdgcn_mfma_i32_16x16x64_i8(AC[m], BARR[n],       \
                                                         acci[m][n], 0, 0, 0); }

// Super-tile: covers (kt, kt+1). Prefetch (kt+2, kt+3); 32 MFMA; optional
// fixup (group g=(kt)>>2 — valid for the odd super where (kt+1)%4==3);
// one vmcnt(0)+barrier at end.
#define SUPER(kt, AC0, AC1, AN0, AN1, DOPF, DOFIX, DOEND) {                    \
  if (DOPF) {                                                                  \
    ALOAD(AN0, (kt) + 2);                                                      \
    __builtin_amdgcn_sched_barrier(0);                                         \
    STAGE_B(((kt) + 2) & 3, (kt) + 2);                                         \
    __builtin_amdgcn_sched_barrier(0);                                         \
    ALOAD(AN1, (kt) + 3);                                                      \
    __builtin_amdgcn_sched_barrier(0);                                         \
    STAGE_B(((kt) + 3) & 3, (kt) + 3);                                         \
    __builtin_amdgcn_sched_barrier(0);                                         \
  }                                                                            \
  {                                                                            \
    int4v b0[4];                                                               \
    _Pragma("unroll")                                                          \
    for (int n = 0; n < 4; ++n) b0[n] = RD_B((kt) & 3, n);                     \
    __builtin_amdgcn_s_setprio(1);                                             \
    MFMA16(AC0, b0)                                                            \
    __builtin_amdgcn_s_setprio(0);                                             \
  }                                                                            \
  {                                                                            \
    int4v b1[4];                                                               \
    _Pragma("unroll")                                                          \
    for (int n = 0; n < 4; ++n) b1[n] = RD_B(((kt) + 1) & 3, n);               \
    __builtin_amdgcn_s_setprio(1);                                             \
    MFMA16(AC1, b1)                                                            \
    __builtin_amdgcn_s_setprio(0);                                             \
  }                                                                            \
  if (DOFIX) {                                                                 \
    const int g = (kt) >> 2;                                                   \
    float4v sxv[4]; float swv[4];                                              \
    _Pragma("unroll")                                                          \
    for (int m = 0; m < 4; ++m)                                                \
      sxv[m] = *(const float4v*)(sxl + g * 128 + wr * 64 + m * 16 + lh * 4);   \
    _Pragma("unroll")                                                          \
    for (int n = 0; n < 4; ++n)                                                \
      swv[n] = swl[g * 128 + wc * 64 + n * 16 + l15];                          \
    _Pragma("unroll")                                                          \
    for (int m = 0; m < 4; ++m)                                                \
      _Pragma("unroll")                                                        \
      for (int n = 0; n < 4; ++n) {                                            \
        _Pragma("unroll")                                                      \
        for (int j = 0; j < 4; ++j)                                            \
          accf[m][n][j] += (float)acci[m][n][j] * (sxv[m][j] * swv[n]);        \
        acci[m][n] = (int4v){0, 0, 0, 0};                                      \
      }                                                                        \
  }                                                                            \
  if (DOEND) { VMW("0") __builtin_amdgcn_s_barrier(); }                        \
}

  int4v A0f[4], A1f[4], A2f[4], A3f[4];

  // prologue: A(0),A(1) to regs; B(0),B(1) staged; drain; publish
  ALOAD(A0f, 0);
  __builtin_amdgcn_sched_barrier(0);
  STAGE_B(0, 0);
  STAGE_B(1, 1);
  __builtin_amdgcn_sched_barrier(0);
  ALOAD(A1f, 1);
  __builtin_amdgcn_sched_barrier(0);
  VMW("0")
  __builtin_amdgcn_s_barrier();

  // steady: 2 supers per iteration (A-set ping-pong); fixup on the odd super
  for (int kt = 0; kt < NTI - 4; kt += 4) {
    SUPER(kt,     A0f, A1f, A2f, A3f, 1, 0, 1)
    SUPER(kt + 2, A2f, A3f, A0f, A1f, 1, 1, 1)
  }
  SUPER(NTI - 4, A0f, A1f, A2f, A3f, 1, 0, 1)   // covers 60,61; prefetch 62,63
  SUPER(NTI - 2, A2f, A3f, A0f, A1f, 0, 1, 0)   // covers 62,63; nothing pending

  // epilogue: bias + fp32 store (C/D map: col=lane&15, row=(lane>>4)*4+j)
#pragma unroll
  for (int m = 0; m < 4; ++m) {
    const int row0 = bm * 128 + wr * 64 + m * 16 + lh * 4;
#pragma unroll
    for (int n = 0; n < 4; ++n) {
      const int col = bn * 128 + wc * 64 + n * 16 + l15;
      const float bv_ = bias_v[n];
#pragma unroll
      for (int j = 0; j < 4; ++j)
        out[(size_t)(row0 + j) * NDIM + col] = accf[m][n][j] + bv_;
    }
  }
#undef SUPER
#undef MFMA16
#undef VMW
#undef RD_B
#undef STAGE_B
#undef ALOAD
}

// ---------------- fallback: fused single-pass (round-1 kernel) ----------------
__global__ __launch_bounds__(256, 2) void clinear_fused(
    const float* __restrict__ x,
    const int* __restrict__ qw,
    const float* __restrict__ scale,
    const float* __restrict__ bias,
    float* __restrict__ out)
{
  __shared__ unsigned char ldsA[128 * 64 * 2];
  __shared__ unsigned char ldsB[128 * 64 * 2];

  const int t = threadIdx.x;
  const int lane = t & 63;
  const int wave = t >> 6;
  const int wr = wave >> 1;
  const int wc = wave & 1;

  const int NBN = NDIM / 128;
  const int bid = blockIdx.x;
  const int cpx = ((MDIM / 128) * NBN) >> 3;
  const int swz = (bid & 7) * cpx + (bid >> 3);
  const int bm = swz / NBN;
  const int bn = swz % NBN;

  const int srow = t >> 1;
  const int shalf = t & 1;
  const float* aptr = x  + (size_t)(bm * 128 + srow) * KDIM + shalf * 32;
  const int*   bptr = qw + (size_t)(bn * 128 + srow) * KDIM + shalf * 32;
  const float* sptr = scale + (size_t)(bn * 128 + srow) * (KDIM / 256);
  const int arx = srow & 7;

  f32x4 acc[4][4];
#pragma unroll
  for (int i = 0; i < 4; ++i)
#pragma unroll
    for (int j = 0; j < 4; ++j)
      acc[i][j] = (f32x4){0.f, 0.f, 0.f, 0.f};

  float bias_v[4];
#pragma unroll
  for (int n = 0; n < 4; ++n)
    bias_v[n] = bias[bn * 128 + wc * 64 + n * 16 + (lane & 15)];

  for (int kt = 0; kt < KDIM / 64; ++kt) {
    const int k0 = kt * 64;
    float4v av[8];
    int4v   bv[8];
#pragma unroll
    for (int j = 0; j < 8; ++j) av[j] = *(const float4v*)(aptr + k0 + 4 * j);
#pragma unroll
    for (int j = 0; j < 8; ++j) bv[j] = *(const int4v*)(bptr + k0 + 4 * j);
    const float inv = 1.0f / sptr[k0 >> 8];

    __syncthreads();
#pragma unroll
    for (int c = 0; c < 4; ++c) {
      short8 pa, pb;
#pragma unroll
      for (int e = 0; e < 8; ++e) {
        const int v = c * 8 + e;
        pa[e] = (short)f2bf(av[v >> 2][v & 3]);
        pb[e] = (short)f2bf((float)bv[v >> 2][v & 3] * inv);
      }
      const int cc = shalf * 4 + c;
      *(short8*)(ldsA + srow * 128 + ((cc ^ arx) << 4)) = pa;
      *(short8*)(ldsB + srow * 128 + ((cc ^ arx) << 4)) = pb;
    }
    __syncthreads();

    short8 af[4][2], bfr[4][2];
#pragma unroll
    for (int m = 0; m < 4; ++m) {
      const int r = wr * 64 + m * 16 + (lane & 15);
      const int rx = r & 7;
#pragma unroll
      for (int ks = 0; ks < 2; ++ks) {
        const int ch = ks * 4 + (lane >> 4);
        af[m][ks] = *(const short8*)(ldsA + r * 128 + ((ch ^ rx) << 4));
      }
    }
#pragma unroll
    for (int n = 0; n < 4; ++n) {
      const int r = wc * 64 + n * 16 + (lane & 15);
      const int rx = r & 7;
#pragma unroll
      for (int ks = 0; ks < 2; ++ks) {
        const int ch = ks * 4 + (lane >> 4);
        bfr[n][ks] = *(const short8*)(ldsB + r * 128 + ((ch ^ rx) << 4));
      }
    }
#pragma unroll
    for (int ks = 0; ks < 2; ++ks)
#pragma unroll
      for (int m = 0; m < 4; ++m)
#pragma unroll
        for (int n = 0; n < 4; ++n)
          acc[m][n] = __builtin_amdgcn_mfma_f32_16x16x32_bf16(
              af[m][ks], bfr[n][ks], acc[m][n], 0, 0, 0);
  }

#pragma unroll
  for (int m = 0; m < 4; ++m) {
    const int row0 = bm * 128 + wr * 64 + m * 16 + (lane >> 4) * 4;
#pragma unroll
    for (int n = 0; n < 4; ++n) {
      const int col = bn * 128 + wc * 64 + n * 16 + (lane & 15);
      const float bv_ = bias_v[n];
#pragma unroll
      for (int j = 0; j < 4; ++j)
        out[(size_t)(row0 + j) * NDIM + col] = acc[m][n][j] + bv_;
    }
  }
}

extern "C" void kernel_launch(void* const* d_in, const int* in_sizes, int n_in,
                              void* d_out, int out_size, void* d_ws, size_t ws_size,
                              hipStream_t stream) {
  const float* x     = (const float*)d_in[0];
  const int*   qw    = (const int*)d_in[1];
  const float* scale = (const float*)d_in[2];
  const float* bias  = (const float*)d_in[3];
  float* out = (float*)d_out;

  if (ws_size >= WS_NEED) {
    char*  aqf = (char*)d_ws + AQ_OFF;
    char*  wqb = (char*)d_ws + WQ_OFF;
    float* sxT = (float*)((char*)d_ws + SXT_OFF);
    float* swT = (float*)((char*)d_ws + SWT_OFF);
    hipLaunchKernelGGL(prep_all, dim3(NXB + NDIM), dim3(256), 0, stream,
                       x, aqf, sxT, qw, scale, wqb, swT);
    hipLaunchKernelGGL(gemm_i8, dim3(NBMI * NBNI), dim3(256), 0, stream,
                       aqf, wqb, sxT, swT, bias, out);
  } else {
    hipLaunchKernelGGL(clinear_fused, dim3((MDIM / 128) * (NDIM / 128)), dim3(256),
                       0, stream, x, qw, scale, bias, out);
  }
}

// Round 18
// 587.582 us; speedup vs baseline: 1.1650x; 1.0600x over previous
//
#include <hip/hip_runtime.h>
#include <hip/hip_bf16.h>
#include <stdint.h>

typedef __attribute__((ext_vector_type(8))) short short8;
typedef __attribute__((ext_vector_type(4))) float f32x4;
typedef __attribute__((ext_vector_type(4))) float float4v;
typedef __attribute__((ext_vector_type(4))) int int4v;

#define MDIM 8192
#define NDIM 11008
#define KDIM 4096
#define BKI  64                /* i8 K-tile */
#define NTI  (KDIM / BKI)      /* 64 K-tiles */
#define NBMI (MDIM / 128)      /* 64 */
#define NBNI (NDIM / 128)      /* 86 */
#define NXB  (MDIM / 16)       /* 512 x row-blocks */

// ws layout (bytes)
#define AQ_OFF  0ull                                  /* A fragment-linear, 32 MB */
#define WQ_OFF  ((size_t)MDIM * KDIM)                 /* 33554432 */
#define SXR_OFF (WQ_OFF + (size_t)NDIM * KDIM)        /* + 45088768: sxr[MDIM] */
#define SWC_OFF (SXR_OFF + (size_t)MDIM * 4)          /* + 32768:    swc[NDIM] */
#define WS_NEED (SWC_OFF + (size_t)NDIM * 4)          /* ~78.7 MB */

static __device__ __forceinline__ unsigned short f2bf(float f) {
  union { float f; unsigned int u; } v;
  v.f = f;
  unsigned int r = v.u + 0x7FFFu + ((v.u >> 16) & 1u);
  return (unsigned short)(r >> 16);
}

#define GLDS16(g, l) __builtin_amdgcn_global_load_lds(                         \
    (const __attribute__((address_space(1))) void*)(g),                        \
    (__attribute__((address_space(3))) void*)(l), 16, 0, 0)

// ---------------- pass 1 (fused) ---------------------------------------------
// blocks [0, NXB): 16 x-rows -> PER-ROW int8 (scale = rowmax/127),
//   fragment-linear aqf (r15-verified transpose machinery, 2 passes over L2-hot x).
// blocks [NXB, NXB+NDIM): w row -> per-COLUMN re-quant q2 = round(q*smin/sg)
//   (exact int in [-127,127]), row-major pack; swc[col] = 1/smin.
__global__ __launch_bounds__(256) void prep_all(
    const float* __restrict__ x, char* __restrict__ aqf, float* __restrict__ sxr,
    const int* __restrict__ qw, const float* __restrict__ scale,
    char* __restrict__ wq, float* __restrict__ swc) {
  const int t = threadIdx.x;
  if (blockIdx.x < NXB) {
    __shared__ char sq[16 * 272];
    const int r16 = blockIdx.x;
    const int row = t >> 4;              // 0..15
    const int seg = t & 15;
    const float* rowp = x + ((size_t)(r16 * 16 + row)) * KDIM;
    // pass 1: row max over this thread's 256 cols, then 16-lane reduce
    float amax = 0.f;
    for (int j = 0; j < 16; ++j) {
      const float* p = rowp + j * 256 + seg * 16;
#pragma unroll
      for (int c = 0; c < 4; ++c) {
        float4v v = *(const float4v*)(p + c * 4);
#pragma unroll
        for (int e = 0; e < 4; ++e) amax = fmaxf(amax, fabsf(v[e]));
      }
    }
#pragma unroll
    for (int d = 1; d < 16; d <<= 1) amax = fmaxf(amax, __shfl_xor(amax, d));
    amax = fmaxf(amax, 1e-20f);
    if (seg == 0) sxr[r16 * 16 + row] = amax * (1.0f / 127.0f);
    const float inv = 127.0f / amax;
    // pass 2: quantize + LDS transpose + fragment-linear write (r15 machinery)
    for (int j = 0; j < 16; ++j) {
      const float* p = rowp + j * 256 + seg * 16;
      int4v o;
#pragma unroll
      for (int c = 0; c < 4; ++c) {
        float4v v = *(const float4v*)(p + c * 4);
        unsigned int r = 0;
#pragma unroll
        for (int e = 0; e < 4; ++e) {
          int q = __float2int_rn(v[e] * inv);
          r |= ((unsigned int)(q & 255)) << (8 * e);
        }
        o[c] = (int)r;
      }
      *(int4v*)(sq + row * 272 + seg * 16) = o;
      __syncthreads();
      {
        const int ktl = t >> 6;
        const int l = t & 63;
        int4v vv = *(const int4v*)(sq + (l & 15) * 272 + ktl * 64 + (l >> 4) * 16);
        *(int4v*)(aqf + (((size_t)r16 * NTI + j * 4 + ktl) << 10) + l * 16) = vv;
      }
      __syncthreads();
    }
  } else {
    const int row = blockIdx.x - NXB;
    __shared__ float sg_s[16];
    if (t < 16) sg_s[t] = scale[(size_t)row * 16 + t];
    __syncthreads();
    float smin = sg_s[0];
#pragma unroll
    for (int g = 1; g < 16; ++g) smin = fminf(smin, sg_s[g]);
    const float ratio = smin / sg_s[t >> 4];   // s_min/s_g <= 1
    const int* p = qw + (size_t)row * KDIM + t * 16;
    int4v v[4];
#pragma unroll
    for (int c = 0; c < 4; ++c) v[c] = *(const int4v*)(p + c * 4);
    int4v o;
#pragma unroll
    for (int c = 0; c < 4; ++c) {
      unsigned int r = 0;
#pragma unroll
      for (int e = 0; e < 4; ++e) {
        int q2 = __float2int_rn((float)v[c][e] * ratio);
        r |= ((unsigned int)(q2 & 255)) << (8 * e);
      }
      o[c] = (int)r;
    }
    *(int4v*)(wq + (size_t)row * KDIM + t * 16) = o;
    if (t == 0) swc[row] = 1.0f / smin;
  }
}

// ---------------- pass 2: 128x128 PURE-int8 GEMM, 3 waves/SIMD --------------
// r15's verified data paths/schedule, with the group-fixup REMOVED (per-row/
// per-col scales -> exact i32 accumulation over full K; fixup in epilogue).
// acci-only (64 regs) -> ~140 total -> 3 blocks/CU. LDS 32KB (B 4-deep only).
// FIFO (r15-exact): per tile issue [A(t+1)x4, B(t+3)x2]; steady vmcnt(8)
// drains {B(t+1) publish, A(t) regs}; prologue vmcnt(8); tail 8->6->4->0.
__global__ __launch_bounds__(256, 3) void gemm_i8(
    const char* __restrict__ aqf, const char* __restrict__ wq,
    const float* __restrict__ sxr, const float* __restrict__ swc,
    const float* __restrict__ bias, float* __restrict__ out)
{
  __shared__ unsigned char ldsB[32768];   // [4][8192]: 8 strips x 16 rows x 64B

  const int t = threadIdx.x;
  const int lane = t & 63;
  const int w = t >> 6;        // wave 0..3
  const int wr = w >> 1;       // 0..1  (A 64-row half)
  const int wc = w & 1;        // 0..1  (B 64-col half)
  const int lh = lane >> 4;    // 0..3
  const int l15 = lane & 15;

  // XCD-bijective swizzle: 5504 = 8 * 688
  const int bid = blockIdx.x;
  const int swz = (bid & 7) * (NBMI * NBNI / 8) + (bid >> 3);
  const int bm = swz / NBNI;
  const int bn = swz % NBNI;

  // B staging (r9/r15): lane-adjacent source, XOR granule
  const int srow16 = lane >> 2;
  const int q = (lane & 3) ^ (srow16 & 3) ^ ((srow16 >> 2) & 3);
  const size_t srcOff = (size_t)srow16 * KDIM + q * 16;
  const char* bS = wq + ((size_t)(bn * 128 + w * 32)) * KDIM + srcOff;
  const int f15 = (l15 & 3) ^ (l15 >> 2);

  // A fragment-linear base: wave's 4 row-blocks start at bm*8 + wr*4
  const char* aF = aqf + (((size_t)(bm * 8 + wr * 4) * NTI) << 10) + lane * 16;

  int4v acci[4][4];
#pragma unroll
  for (int m = 0; m < 4; ++m)
#pragma unroll
    for (int n = 0; n < 4; ++n) acci[m][n] = (int4v){0, 0, 0, 0};

#define ALOAD(ABUF, kt) {                                                      \
  _Pragma("unroll")                                                            \
  for (int m = 0; m < 4; ++m)                                                  \
    ABUF[m] = *(const int4v*)(aF + (((size_t)m * NTI + (kt)) << 10)); }

#define STAGE_B(buf, kt) {                                                     \
  GLDS16(bS + (kt) * BKI,             ldsB + (buf) * 8192 + w * 2048);         \
  GLDS16(bS + 16 * KDIM + (kt) * BKI, ldsB + (buf) * 8192 + w * 2048 + 1024); }

#define RD_B(buf, n) (*(const int4v*)(ldsB + (buf) * 8192 + wc * 4096 +        \
                      (n) * 1024 + l15 * 64 + ((lh ^ f15) << 4)))

#define VMW(N) asm volatile("s_waitcnt vmcnt(" N ")" ::: "memory");

// tile t (bbuf = t&3): issue A(t+1)->ANXT, B-stage(t+3); ds_read B(t);
// counted wait; 16 MFMA on ACUR; barrier.
#define TILE(bbuf, kt, ACUR, ANXT, DOLOADA, DOSTAGEB, WAITN, DOBAR) {          \
  if (DOLOADA) ALOAD(ANXT, (kt) + 1);                                          \
  __builtin_amdgcn_sched_barrier(0);                                           \
  if (DOSTAGEB) STAGE_B(((bbuf) + 3) & 3, (kt) + 3);                           \
  __builtin_amdgcn_sched_barrier(0);                                           \
  int4v b[4];                                                                  \
  _Pragma("unroll")                                                            \
  for (int n = 0; n < 4; ++n) b[n] = RD_B(bbuf, n);                            \
  VMW(WAITN)                                                                   \
  __builtin_amdgcn_sched_barrier(0);                                           \
  __builtin_amdgcn_s_setprio(1);                                               \
  _Pragma("unroll")                                                            \
  for (int m = 0; m < 4; ++m)                                                  \
    _Pragma("unroll")                                                          \
    for (int n = 0; n < 4; ++n)                                                \
      acci[m][n] = __builtin_amdgcn_mfma_i32_16x16x64_i8(ACUR[m], b[n],        \
                                                         acci[m][n], 0, 0, 0); \
  __builtin_amdgcn_s_setprio(0);                                               \
  if (DOBAR) __builtin_amdgcn_s_barrier(); }

  int4v A0f[4], A1f[4];

  // prologue (FIFO matches steady): B0, B1, A0, B2; drain B0 -> vmcnt(8)
  STAGE_B(0, 0);
  STAGE_B(1, 1);
  __builtin_amdgcn_sched_barrier(0);
  ALOAD(A0f, 0);
  __builtin_amdgcn_sched_barrier(0);
  STAGE_B(2, 2);
  __builtin_amdgcn_sched_barrier(0);
  VMW("8")
  __builtin_amdgcn_s_barrier();

  // steady: entering t: [B(t+1)2, A(t)4, B(t+2)2]=8; +6; vmcnt(8) drains
  // B(t+1)+A(t) exactly.
  for (int kt = 0; kt < NTI - 4; kt += 4) {
    TILE(0, kt,     A0f, A1f, 1, 1, "8", 1)
    TILE(1, kt + 1, A1f, A0f, 1, 1, "8", 1)
    TILE(2, kt + 2, A0f, A1f, 1, 1, "8", 1)
    TILE(3, kt + 3, A1f, A0f, 1, 1, "8", 1)
  }
  // tail: t60 steady (stages B63); t61/62 no B-stage; t63 nothing
  TILE(0, NTI - 4, A0f, A1f, 1, 1, "8", 1)
  TILE(1, NTI - 3, A1f, A0f, 1, 0, "6", 1)
  TILE(2, NTI - 2, A0f, A1f, 1, 0, "4", 1)
  TILE(3, NTI - 1, A1f, A0f, 0, 0, "0", 0)

  // epilogue: out = acci * sxr[row] * swc[col] + bias
  float swv[4], bias_v[4];
#pragma unroll
  for (int n = 0; n < 4; ++n) {
    const int col = bn * 128 + wc * 64 + n * 16 + l15;
    swv[n] = swc[col];
    bias_v[n] = bias[col];
  }
#pragma unroll
  for (int m = 0; m < 4; ++m) {
    const int row0 = bm * 128 + wr * 64 + m * 16 + lh * 4;
    float4v sxm = *(const float4v*)(sxr + row0);   // rows row0..row0+3
#pragma unroll
    for (int n = 0; n < 4; ++n) {
      const int col = bn * 128 + wc * 64 + n * 16 + l15;
      const float s_ = swv[n];
      const float bv_ = bias_v[n];
#pragma unroll
      for (int j = 0; j < 4; ++j)
        out[(size_t)(row0 + j) * NDIM + col] =
            (float)acci[m][n][j] * (sxm[j] * s_) + bv_;
    }
  }
#undef TILE
#undef VMW
#undef RD_B
#undef STAGE_B
#undef ALOAD
}

// ---------------- fallback: fused single-pass (round-1 kernel) ----------------
__global__ __launch_bounds__(256, 2) void clinear_fused(
    const float* __restrict__ x,
    const int* __restrict__ qw,
    const float* __restrict__ scale,
    const float* __restrict__ bias,
    float* __restrict__ out)
{
  __shared__ unsigned char ldsA[128 * 64 * 2];
  __shared__ unsigned char ldsB[128 * 64 * 2];

  const int t = threadIdx.x;
  const int lane = t & 63;
  const int wave = t >> 6;
  const int wr = wave >> 1;
  const int wc = wave & 1;

  const int NBN = NDIM / 128;
  const int bid = blockIdx.x;
  const int cpx = ((MDIM / 128) * NBN) >> 3;
  const int swz = (bid & 7) * cpx + (bid >> 3);
  const int bm = swz / NBN;
  const int bn = swz % NBN;

  const int srow = t >> 1;
  const int shalf = t & 1;
  const float* aptr = x  + (size_t)(bm * 128 + srow) * KDIM + shalf * 32;
  const int*   bptr = qw + (size_t)(bn * 128 + srow) * KDIM + shalf * 32;
  const float* sptr = scale + (size_t)(bn * 128 + srow) * (KDIM / 256);
  const int arx = srow & 7;

  f32x4 acc[4][4];
#pragma unroll
  for (int i = 0; i < 4; ++i)
#pragma unroll
    for (int j = 0; j < 4; ++j)
      acc[i][j] = (f32x4){0.f, 0.f, 0.f, 0.f};

  float bias_v[4];
#pragma unroll
  for (int n = 0; n < 4; ++n)
    bias_v[n] = bias[bn * 128 + wc * 64 + n * 16 + (lane & 15)];

  for (int kt = 0; kt < KDIM / 64; ++kt) {
    const int k0 = kt * 64;
    float4v av[8];
    int4v   bv[8];
#pragma unroll
    for (int j = 0; j < 8; ++j) av[j] = *(const float4v*)(aptr + k0 + 4 * j);
#pragma unroll
    for (int j = 0; j < 8; ++j) bv[j] = *(const int4v*)(bptr + k0 + 4 * j);
    const float inv = 1.0f / sptr[k0 >> 8];

    __syncthreads();
#pragma unroll
    for (int c = 0; c < 4; ++c) {
      short8 pa, pb;
#pragma unroll
      for (int e = 0; e < 8; ++e) {
        const int v = c * 8 + e;
        pa[e] = (short)f2bf(av[v >> 2][v & 3]);
        pb[e] = (short)f2bf((float)bv[v >> 2][v & 3] * inv);
      }
      const int cc = shalf * 4 + c;
      *(short8*)(ldsA + srow * 128 + ((cc ^ arx) << 4)) = pa;
      *(short8*)(ldsB + srow * 128 + ((cc ^ arx) << 4)) = pb;
    }
    __syncthreads();

    short8 af[4][2], bfr[4][2];
#pragma unroll
    for (int m = 0; m < 4; ++m) {
      const int r = wr * 64 + m * 16 + (lane & 15);
      const int rx = r & 7;
#pragma unroll
      for (int ks = 0; ks < 2; ++ks) {
        const int ch = ks * 4 + (lane >> 4);
        af[m][ks] = *(const short8*)(ldsA + r * 128 + ((ch ^ rx) << 4));
      }
    }
#pragma unroll
    for (int n = 0; n < 4; ++n) {
      const int r = wc * 64 + n * 16 + (lane & 15);
      const int rx = r & 7;
#pragma unroll
      for (int ks = 0; ks < 2; ++ks) {
        const int ch = ks * 4 + (lane >> 4);
        bfr[n][ks] = *(const short8*)(ldsB + r * 128 + ((ch ^ rx) << 4));
      }
    }
#pragma unroll
    for (int ks = 0; ks < 2; ++ks)
#pragma unroll
      for (int m = 0; m < 4; ++m)
#pragma unroll
        for (int n = 0; n < 4; ++n)
          acc[m][n] = __builtin_amdgcn_mfma_f32_16x16x32_bf16(
              af[m][ks], bfr[n][ks], acc[m][n], 0, 0, 0);
  }

#pragma unroll
  for (int m = 0; m < 4; ++m) {
    const int row0 = bm * 128 + wr * 64 + m * 16 + (lane >> 4) * 4;
#pragma unroll
    for (int n = 0; n < 4; ++n) {
      const int col = bn * 128 + wc * 64 + n * 16 + (lane & 15);
      const float bv_ = bias_v[n];
#pragma unroll
      for (int j = 0; j < 4; ++j)
        out[(size_t)(row0 + j) * NDIM + col] = acc[m][n][j] + bv_;
    }
  }
}

extern "C" void kernel_launch(void* const* d_in, const int* in_sizes, int n_in,
                              void* d_out, int out_size, void* d_ws, size_t ws_size,
                              hipStream_t stream) {
  const float* x     = (const float*)d_in[0];
  const int*   qw    = (const int*)d_in[1];
  const float* scale = (const float*)d_in[2];
  const float* bias  = (const float*)d_in[3];
  float* out = (float*)d_out;

  if (ws_size >= WS_NEED) {
    char*  aqf = (char*)d_ws + AQ_OFF;
    char*  wqb = (char*)d_ws + WQ_OFF;
    float* sxr = (float*)((char*)d_ws + SXR_OFF);
    float* swc = (float*)((char*)d_ws + SWC_OFF);
    hipLaunchKernelGGL(prep_all, dim3(NXB + NDIM), dim3(256), 0, stream,
                       x, aqf, sxr, qw, scale, wqb, swc);
    hipLaunchKernelGGL(gemm_i8, dim3(NBMI * NBNI), dim3(256), 0, stream,
                       aqf, wqb, sxr, swc, bias, out);
  } else {
    hipLaunchKernelGGL(clinear_fused, dim3((MDIM / 128) * (NDIM / 128)), dim3(256),
                       0, stream, x, qw, scale, bias, out);
  }
}

// Round 19
// 576.735 us; speedup vs baseline: 1.1869x; 1.0188x over previous
//
#include <hip/hip_runtime.h>
#include <hip/hip_bf16.h>
#include <stdint.h>

typedef __attribute__((ext_vector_type(8))) short short8;
typedef __attribute__((ext_vector_type(4))) float f32x4;
typedef __attribute__((ext_vector_type(4))) float float4v;
typedef __attribute__((ext_vector_type(4))) int int4v;

#define MDIM 8192
#define NDIM 11008
#define KDIM 4096
#define BKI  64                /* i8 K-tile */
#define NTI  (KDIM / BKI)      /* 64 K-tiles */
#define NBMI (MDIM / 128)      /* 64 */
#define NBNI (NDIM / 128)      /* 86 */
#define NXB  (MDIM / 16)       /* 512 x row-blocks */

// ws layout (bytes)
#define AQ_OFF  0ull                                  /* A fragment-linear, 32 MB */
#define WQ_OFF  ((size_t)MDIM * KDIM)                 /* 33554432 */
#define SXR_OFF (WQ_OFF + (size_t)NDIM * KDIM)        /* + 45088768: sxr[MDIM] */
#define SWC_OFF (SXR_OFF + (size_t)MDIM * 4)          /* + 32768:    swc[NDIM] */
#define WS_NEED (SWC_OFF + (size_t)NDIM * 4)          /* ~78.7 MB */

static __device__ __forceinline__ unsigned short f2bf(float f) {
  union { float f; unsigned int u; } v;
  v.f = f;
  unsigned int r = v.u + 0x7FFFu + ((v.u >> 16) & 1u);
  return (unsigned short)(r >> 16);
}

#define GLDS16(g, l) __builtin_amdgcn_global_load_lds(                         \
    (const __attribute__((address_space(1))) void*)(g),                        \
    (__attribute__((address_space(3))) void*)(l), 16, 0, 0)

// ---------------- pass 1 (fused) — r18-verified ------------------------------
__global__ __launch_bounds__(256) void prep_all(
    const float* __restrict__ x, char* __restrict__ aqf, float* __restrict__ sxr,
    const int* __restrict__ qw, const float* __restrict__ scale,
    char* __restrict__ wq, float* __restrict__ swc) {
  const int t = threadIdx.x;
  if (blockIdx.x < NXB) {
    __shared__ char sq[16 * 272];
    const int r16 = blockIdx.x;
    const int row = t >> 4;              // 0..15
    const int seg = t & 15;
    const float* rowp = x + ((size_t)(r16 * 16 + row)) * KDIM;
    float amax = 0.f;
    for (int j = 0; j < 16; ++j) {
      const float* p = rowp + j * 256 + seg * 16;
#pragma unroll
      for (int c = 0; c < 4; ++c) {
        float4v v = *(const float4v*)(p + c * 4);
#pragma unroll
        for (int e = 0; e < 4; ++e) amax = fmaxf(amax, fabsf(v[e]));
      }
    }
#pragma unroll
    for (int d = 1; d < 16; d <<= 1) amax = fmaxf(amax, __shfl_xor(amax, d));
    amax = fmaxf(amax, 1e-20f);
    if (seg == 0) sxr[r16 * 16 + row] = amax * (1.0f / 127.0f);
    const float inv = 127.0f / amax;
    for (int j = 0; j < 16; ++j) {
      const float* p = rowp + j * 256 + seg * 16;
      int4v o;
#pragma unroll
      for (int c = 0; c < 4; ++c) {
        float4v v = *(const float4v*)(p + c * 4);
        unsigned int r = 0;
#pragma unroll
        for (int e = 0; e < 4; ++e) {
          int q = __float2int_rn(v[e] * inv);
          r |= ((unsigned int)(q & 255)) << (8 * e);
        }
        o[c] = (int)r;
      }
      *(int4v*)(sq + row * 272 + seg * 16) = o;
      __syncthreads();
      {
        const int ktl = t >> 6;
        const int l = t & 63;
        int4v vv = *(const int4v*)(sq + (l & 15) * 272 + ktl * 64 + (l >> 4) * 16);
        *(int4v*)(aqf + (((size_t)r16 * NTI + j * 4 + ktl) << 10) + l * 16) = vv;
      }
      __syncthreads();
    }
  } else {
    const int row = blockIdx.x - NXB;
    __shared__ float sg_s[16];
    if (t < 16) sg_s[t] = scale[(size_t)row * 16 + t];
    __syncthreads();
    float smin = sg_s[0];
#pragma unroll
    for (int g = 1; g < 16; ++g) smin = fminf(smin, sg_s[g]);
    const float ratio = smin / sg_s[t >> 4];
    const int* p = qw + (size_t)row * KDIM + t * 16;
    int4v v[4];
#pragma unroll
    for (int c = 0; c < 4; ++c) v[c] = *(const int4v*)(p + c * 4);
    int4v o;
#pragma unroll
    for (int c = 0; c < 4; ++c) {
      unsigned int r = 0;
#pragma unroll
      for (int e = 0; e < 4; ++e) {
        int q2 = __float2int_rn((float)v[c][e] * ratio);
        r |= ((unsigned int)(q2 & 255)) << (8 * e);
      }
      o[c] = (int)r;
    }
    *(int4v*)(wq + (size_t)row * KDIM + t * 16) = o;
    if (t == 0) swc[row] = 1.0f / smin;
  }
}

// ---------------- pass 2: 128x128 pure-i8 GEMM, super-tile + 3 blocks/CU -----
// r18's data paths (A fragment-linear direct, B lane-adjacent GLDS + XOR read,
// 4-deep) with ONE vmcnt(0)+barrier per 2 K-tiles (r17's verified scheme).
// Super S covers (kt,kt+1): loads A(kt+2),A(kt+3) to regs (ping-pong pairs),
// stages B(kt+2),B(kt+3) into the disjoint bufs, 32 MFMA, drain+barrier.
__global__ __launch_bounds__(256, 3) void gemm_i8(
    const char* __restrict__ aqf, const char* __restrict__ wq,
    const float* __restrict__ sxr, const float* __restrict__ swc,
    const float* __restrict__ bias, float* __restrict__ out)
{
  __shared__ unsigned char ldsB[32768];   // [4][8192]: 8 strips x 16 rows x 64B

  const int t = threadIdx.x;
  const int lane = t & 63;
  const int w = t >> 6;        // wave 0..3
  const int wr = w >> 1;       // 0..1  (A 64-row half)
  const int wc = w & 1;        // 0..1  (B 64-col half)
  const int lh = lane >> 4;    // 0..3
  const int l15 = lane & 15;

  // XCD-bijective swizzle: 5504 = 8 * 688
  const int bid = blockIdx.x;
  const int swz = (bid & 7) * (NBMI * NBNI / 8) + (bid >> 3);
  const int bm = swz / NBNI;
  const int bn = swz % NBNI;

  // B staging: lane-adjacent source, XOR granule
  const int srow16 = lane >> 2;
  const int q = (lane & 3) ^ (srow16 & 3) ^ ((srow16 >> 2) & 3);
  const size_t srcOff = (size_t)srow16 * KDIM + q * 16;
  const char* bS = wq + ((size_t)(bn * 128 + w * 32)) * KDIM + srcOff;
  const int f15 = (l15 & 3) ^ (l15 >> 2);

  // A fragment-linear base: wave's 4 row-blocks start at bm*8 + wr*4
  const char* aF = aqf + (((size_t)(bm * 8 + wr * 4) * NTI) << 10) + lane * 16;

  int4v acci[4][4];
#pragma unroll
  for (int m = 0; m < 4; ++m)
#pragma unroll
    for (int n = 0; n < 4; ++n) acci[m][n] = (int4v){0, 0, 0, 0};

#define ALOAD(ABUF, kt) {                                                      \
  _Pragma("unroll")                                                            \
  for (int m = 0; m < 4; ++m)                                                  \
    ABUF[m] = *(const int4v*)(aF + (((size_t)m * NTI + (kt)) << 10)); }

#define STAGE_B(buf, kt) {                                                     \
  GLDS16(bS + (kt) * BKI,             ldsB + (buf) * 8192 + w * 2048);         \
  GLDS16(bS + 16 * KDIM + (kt) * BKI, ldsB + (buf) * 8192 + w * 2048 + 1024); }

#define RD_B(buf, n) (*(const int4v*)(ldsB + (buf) * 8192 + wc * 4096 +        \
                      (n) * 1024 + l15 * 64 + ((lh ^ f15) << 4)))

#define VMW(N) asm volatile("s_waitcnt vmcnt(" N ")" ::: "memory");

#define MFMA16(AC, BARR) {                                                     \
  _Pragma("unroll")                                                            \
  for (int m = 0; m < 4; ++m)                                                  \
    _Pragma("unroll")                                                          \
    for (int n = 0; n < 4; ++n)                                                \
      acci[m][n] = __builtin_amdgcn_mfma_i32_16x16x64_i8(AC[m], BARR[n],       \
                                                         acci[m][n], 0, 0, 0); }

// Super covers (kt, kt+1): prefetch A(kt+2),A(kt+3) into AN0/AN1 + stage
// B(kt+2),B(kt+3) (disjoint bufs); 2 x {4 ds_read + 16 MFMA}; one
// vmcnt(0)+barrier (drain budget = full super > HBM latency).
#define SUPER(kt, AC0, AC1, AN0, AN1, DOPF, DOEND) {                           \
  if (DOPF) {                                                                  \
    ALOAD(AN0, (kt) + 2);                                                      \
    __builtin_amdgcn_sched_barrier(0);                                         \
    ALOAD(AN1, (kt) + 3);                                                      \
    __builtin_amdgcn_sched_barrier(0);                                         \
    STAGE_B(((kt) + 2) & 3, (kt) + 2);                                         \
    STAGE_B(((kt) + 3) & 3, (kt) + 3);                                         \
    __builtin_amdgcn_sched_barrier(0);                                         \
  }                                                                            \
  {                                                                            \
    int4v b0[4];                                                               \
    _Pragma("unroll")                                                          \
    for (int n = 0; n < 4; ++n) b0[n] = RD_B((kt) & 3, n);                     \
    __builtin_amdgcn_s_setprio(1);                                             \
    MFMA16(AC0, b0)                                                            \
    __builtin_amdgcn_s_setprio(0);                                             \
  }                                                                            \
  {                                                                            \
    int4v b1[4];                                                               \
    _Pragma("unroll")                                                          \
    for (int n = 0; n < 4; ++n) b1[n] = RD_B(((kt) + 1) & 3, n);               \
    __builtin_amdgcn_s_setprio(1);                                             \
    MFMA16(AC1, b1)                                                            \
    __builtin_amdgcn_s_setprio(0);                                             \
  }                                                                            \
  if (DOEND) { VMW("0") __builtin_amdgcn_s_barrier(); }                        \
}

  int4v Aa0[4], Ab0[4], Aa1[4], Ab1[4];

  // prologue: B(0),B(1) staged; A(0),A(1) to regs; drain; publish
  STAGE_B(0, 0);
  STAGE_B(1, 1);
  __builtin_amdgcn_sched_barrier(0);
  ALOAD(Aa0, 0);
  ALOAD(Ab0, 1);
  __builtin_amdgcn_sched_barrier(0);
  VMW("0")
  __builtin_amdgcn_s_barrier();

  // steady: 2 supers per iteration (A pair ping-pong)
  for (int kt = 0; kt < NTI - 4; kt += 4) {
    SUPER(kt,     Aa0, Ab0, Aa1, Ab1, 1, 1)
    SUPER(kt + 2, Aa1, Ab1, Aa0, Ab0, 1, 1)
  }
  SUPER(NTI - 4, Aa0, Ab0, Aa1, Ab1, 1, 1)   // covers 60,61; prefetch 62,63
  SUPER(NTI - 2, Aa1, Ab1, Aa0, Ab0, 0, 0)   // covers 62,63; nothing pending

  // epilogue: out = acci * sxr[row] * swc[col] + bias
  float swv[4], bias_v[4];
#pragma unroll
  for (int n = 0; n < 4; ++n) {
    const int col = bn * 128 + wc * 64 + n * 16 + l15;
    swv[n] = swc[col];
    bias_v[n] = bias[col];
  }
#pragma unroll
  for (int m = 0; m < 4; ++m) {
    const int row0 = bm * 128 + wr * 64 + m * 16 + lh * 4;
    float4v sxm = *(const float4v*)(sxr + row0);
#pragma unroll
    for (int n = 0; n < 4; ++n) {
      const int col = bn * 128 + wc * 64 + n * 16 + l15;
      const float s_ = swv[n];
      const float bv_ = bias_v[n];
#pragma unroll
      for (int j = 0; j < 4; ++j)
        out[(size_t)(row0 + j) * NDIM + col] =
            (float)acci[m][n][j] * (sxm[j] * s_) + bv_;
    }
  }
#undef SUPER
#undef MFMA16
#undef VMW
#undef RD_B
#undef STAGE_B
#undef ALOAD
}

// ---------------- fallback: fused single-pass (round-1 kernel) ----------------
__global__ __launch_bounds__(256, 2) void clinear_fused(
    const float* __restrict__ x,
    const int* __restrict__ qw,
    const float* __restrict__ scale,
    const float* __restrict__ bias,
    float* __restrict__ out)
{
  __shared__ unsigned char ldsA[128 * 64 * 2];
  __shared__ unsigned char ldsB[128 * 64 * 2];

  const int t = threadIdx.x;
  const int lane = t & 63;
  const int wave = t >> 6;
  const int wr = wave >> 1;
  const int wc = wave & 1;

  const int NBN = NDIM / 128;
  const int bid = blockIdx.x;
  const int cpx = ((MDIM / 128) * NBN) >> 3;
  const int swz = (bid & 7) * cpx + (bid >> 3);
  const int bm = swz / NBN;
  const int bn = swz % NBN;

  const int srow = t >> 1;
  const int shalf = t & 1;
  const float* aptr = x  + (size_t)(bm * 128 + srow) * KDIM + shalf * 32;
  const int*   bptr = qw + (size_t)(bn * 128 + srow) * KDIM + shalf * 32;
  const float* sptr = scale + (size_t)(bn * 128 + srow) * (KDIM / 256);
  const int arx = srow & 7;

  f32x4 acc[4][4];
#pragma unroll
  for (int i = 0; i < 4; ++i)
#pragma unroll
    for (int j = 0; j < 4; ++j)
      acc[i][j] = (f32x4){0.f, 0.f, 0.f, 0.f};

  float bias_v[4];
#pragma unroll
  for (int n = 0; n < 4; ++n)
    bias_v[n] = bias[bn * 128 + wc * 64 + n * 16 + (lane & 15)];

  for (int kt = 0; kt < KDIM / 64; ++kt) {
    const int k0 = kt * 64;
    float4v av[8];
    int4v   bv[8];
#pragma unroll
    for (int j = 0; j < 8; ++j) av[j] = *(const float4v*)(aptr + k0 + 4 * j);
#pragma unroll
    for (int j = 0; j < 8; ++j) bv[j] = *(const int4v*)(bptr + k0 + 4 * j);
    const float inv = 1.0f / sptr[k0 >> 8];

    __syncthreads();
#pragma unroll
    for (int c = 0; c < 4; ++c) {
      short8 pa, pb;
#pragma unroll
      for (int e = 0; e < 8; ++e) {
        const int v = c * 8 + e;
        pa[e] = (short)f2bf(av[v >> 2][v & 3]);
        pb[e] = (short)f2bf((float)bv[v >> 2][v & 3] * inv);
      }
      const int cc = shalf * 4 + c;
      *(short8*)(ldsA + srow * 128 + ((cc ^ arx) << 4)) = pa;
      *(short8*)(ldsB + srow * 128 + ((cc ^ arx) << 4)) = pb;
    }
    __syncthreads();

    short8 af[4][2], bfr[4][2];
#pragma unroll
    for (int m = 0; m < 4; ++m) {
      const int r = wr * 64 + m * 16 + (lane & 15);
      const int rx = r & 7;
#pragma unroll
      for (int ks = 0; ks < 2; ++ks) {
        const int ch = ks * 4 + (lane >> 4);
        af[m][ks] = *(const short8*)(ldsA + r * 128 + ((ch ^ rx) << 4));
      }
    }
#pragma unroll
    for (int n = 0; n < 4; ++n) {
      const int r = wc * 64 + n * 16 + (lane & 15);
      const int rx = r & 7;
#pragma unroll
      for (int ks = 0; ks < 2; ++ks) {
        const int ch = ks * 4 + (lane >> 4);
        bfr[n][ks] = *(const short8*)(ldsB + r * 128 + ((ch ^ rx) << 4));
      }
    }
#pragma unroll
    for (int ks = 0; ks < 2; ++ks)
#pragma unroll
      for (int m = 0; m < 4; ++m)
#pragma unroll
        for (int n = 0; n < 4; ++n)
          acc[m][n] = __builtin_amdgcn_mfma_f32_16x16x32_bf16(
              af[m][ks], bfr[n][ks], acc[m][n], 0, 0, 0);
  }

#pragma unroll
  for (int m = 0; m < 4; ++m) {
    const int row0 = bm * 128 + wr * 64 + m * 16 + (lane >> 4) * 4;
#pragma unroll
    for (int n = 0; n < 4; ++n) {
      const int col = bn * 128 + wc * 64 + n * 16 + (lane & 15);
      const float bv_ = bias_v[n];
#pragma unroll
      for (int j = 0; j < 4; ++j)
        out[(size_t)(row0 + j) * NDIM + col] = acc[m][n][j] + bv_;
    }
  }
}

extern "C" void kernel_launch(void* const* d_in, const int* in_sizes, int n_in,
                              void* d_out, int out_size, void* d_ws, size_t ws_size,
                              hipStream_t stream) {
  const float* x     = (const float*)d_in[0];
  const int*   qw    = (const int*)d_in[1];
  const float* scale = (const float*)d_in[2];
  const float* bias  = (const float*)d_in[3];
  float* out = (float*)d_out;

  if (ws_size >= WS_NEED) {
    char*  aqf = (char*)d_ws + AQ_OFF;
    char*  wqb = (char*)d_ws + WQ_OFF;
    float* sxr = (float*)((char*)d_ws + SXR_OFF);
    float* swc = (float*)((char*)d_ws + SWC_OFF);
    hipLaunchKernelGGL(prep_all, dim3(NXB + NDIM), dim3(256), 0, stream,
                       x, aqf, sxr, qw, scale, wqb, swc);
    hipLaunchKernelGGL(gemm_i8, dim3(NBMI * NBNI), dim3(256), 0, stream,
                       aqf, wqb, sxr, swc, bias, out);
  } else {
    hipLaunchKernelGGL(clinear_fused, dim3((MDIM / 128) * (NDIM / 128)), dim3(256),
                       0, stream, x, qw, scale, bias, out);
  }
}